// Round 5
// baseline (318.002 us; speedup 1.0000x reference)
//
#include <hip/hip_runtime.h>

// Problem constants (from reference): B=32, L=4096, D=128, N=5, V=128
constexpr int Bn = 32;
constexpr int Ln = 4096;
constexpr int Dn = 128;
constexpr int Vn = 128;
constexpr int N1 = 4;   // N - 1 context slots
constexpr int ROWS = N1 * Vn;  // 512 table rows

typedef float vfloat4 __attribute__((ext_vector_type(4)));  // native vec for nontemporal builtins

// R11: SINGLE fused kernel, low-register phase-1 (R10 retry).
// History: R7 eighth-slices broke store granularity (+8us). R8 quarter-slices
// fixed it (full 128B-line NT stores). R9 gather swizzle NEUTRAL -> gather never
// critical; the ngram loop is store-bound (~13us). Remaining ~30us of the 92us
// total was dispatch structure (build kernel + T global round-trip + launch gap),
// so R10 fused everything into one kernel: each block builds its own 64 KiB
// v-quarter table DIRECTLY in LDS (redundant compute ~6.8us VALU at 1 block/CU,
// against an otherwise idle VALU pipe), then streams 2048 positions of output.
// R10's bench died (container failed twice); its phase-1 cached a full emb row in
// 128 VGPRs under a 256-VGPR cap + full 4x2x32 unroll = spill/compile risk.
// R11 phase-1: thread owns one float4-column x 8 rows instead. Per wave, emb
// reads = 8 broadcast rows and W reads = 8 distinct 16B slots (TA-coalesced,
// L1-resident). ~60 VGPR, outer loop rolled.
//
// LDS write swizzle (validated R9, involution on both sides): float4 index
// r*8 + (vq ^ (t&7)), with r = k*128 + t so r&7 == t&7. Un-swizzled, phase-2's
// gather (8 same-vq lanes, random rows) piles onto one bank group.
__global__ void __launch_bounds__(512, 2)
fused_ngram_kernel(const int* __restrict__ x,
                   const float* __restrict__ emb,
                   const float* __restrict__ W,
                   const float* __restrict__ bias,
                   float* __restrict__ out) {
    __shared__ float lds[ROWS * 32];  // 65536 B exactly

    const int q  = blockIdx.x & 3;   // v-quarter
    const int ph = blockIdx.x >> 2;  // position half-block 0..63 (2048 positions)

    const int vq = threadIdx.x & 7;   // float4 column within the 32-float quarter
    const float4 bias4 = ((const float4*)bias)[q * 8 + vq];

    // ---------------- Phase 1: build table quarter in LDS ----------------
    {
        const int r0 = threadIdx.x >> 3;          // 0..63
        const int v0 = q * 32 + vq * 4;           // first of 4 v values
        const float* Wb = W + (size_t)v0 * (Dn * N1);

        for (int rr = 0; rr < 8; ++rr) {
            const int r = rr * 64 + r0;           // table row 0..511
            const int t = r & 127;                // token
            const int k = r >> 7;                 // slot
            const float4* e  = (const float4*)(emb + (size_t)t * Dn);
            const float4* w0 = (const float4*)(Wb + 0 * (size_t)(Dn * N1) + k * Dn);
            const float4* w1 = (const float4*)(Wb + 1 * (size_t)(Dn * N1) + k * Dn);
            const float4* w2 = (const float4*)(Wb + 2 * (size_t)(Dn * N1) + k * Dn);
            const float4* w3 = (const float4*)(Wb + 3 * (size_t)(Dn * N1) + k * Dn);

            // 4 independent dot-128 chains (ILP), component-wise accumulate
            float4 s0 = {0, 0, 0, 0}, s1 = {0, 0, 0, 0};
            float4 s2 = {0, 0, 0, 0}, s3 = {0, 0, 0, 0};
#pragma unroll
            for (int i = 0; i < 32; ++i) {
                const float4 ev = e[i];
                float4 a = w0[i]; s0.x += a.x * ev.x; s0.y += a.y * ev.y; s0.z += a.z * ev.z; s0.w += a.w * ev.w;
                float4 b = w1[i]; s1.x += b.x * ev.x; s1.y += b.y * ev.y; s1.z += b.z * ev.z; s1.w += b.w * ev.w;
                float4 c = w2[i]; s2.x += c.x * ev.x; s2.y += c.y * ev.y; s2.z += c.z * ev.z; s2.w += c.w * ev.w;
                float4 d = w3[i]; s3.x += d.x * ev.x; s3.y += d.y * ev.y; s3.z += d.z * ev.z; s3.w += d.w * ev.w;
            }
            float4 acc;
            acc.x = s0.x + s0.y + s0.z + s0.w;
            acc.y = s1.x + s1.y + s1.z + s1.w;
            acc.z = s2.x + s2.y + s2.z + s2.w;
            acc.w = s3.x + s3.y + s3.z + s3.w;
            if (k == 0) {  // fold bias into slot-0 table
                acc.x += bias4.x; acc.y += bias4.y; acc.z += bias4.z; acc.w += bias4.w;
            }
            ((float4*)lds)[r * 8 + (vq ^ (t & 7))] = acc;  // swizzled write
        }
    }
    __syncthreads();

    // ---------------- Phase 2: gather + NT store stream (proven R8/R9 loop) ----
    const int gl = threadIdx.x >> 3;  // position group 0..63
    const vfloat4* lv   = (const vfloat4*)lds;
    vfloat4*       outq = (vfloat4*)out;

#pragma unroll
    for (int it = 0; it < 8; ++it) {
        const int basepos = ph * 2048 + it * 256 + gl * 4;  // 4-aligned
        vfloat4*  ob      = outq + (size_t)basepos * 32 + q * 8 + vq;

        if ((basepos & (Ln - 1)) == 0) {
            // positions j=0..3 of a batch row: bias-only
            const vfloat4 bv = {bias4.x, bias4.y, bias4.z, bias4.w};
#pragma unroll
            for (int i = 0; i < 4; ++i)
                __builtin_nontemporal_store(bv, ob + i * 32);
            continue;
        }

        // token window w[0..6] = x[basepos-4 .. basepos+2]; both int4 loads aligned
        const int4 xa = *(const int4*)(x + basepos - 4);
        const int4 xb = *(const int4*)(x + basepos);
        const int  w[7] = {xa.x, xa.y, xa.z, xa.w, xb.x, xb.y, xb.z};

#pragma unroll
        for (int i = 0; i < 4; ++i) {
            // row r = k*128 + tok; swizzled float4 index = r*8 + (vq ^ (tok&7))
            vfloat4 a = lv[(w[i] << 3) + (vq ^ (w[i] & 7))];
#pragma unroll
            for (int k = 1; k < N1; ++k) {
                const int tok = w[i + k];
                a += lv[((k * Vn + tok) << 3) + (vq ^ (tok & 7))];
            }
            __builtin_nontemporal_store(a, ob + i * 32);  // R6: nt stores required
        }
    }
}

extern "C" void kernel_launch(void* const* d_in, const int* in_sizes, int n_in,
                              void* d_out, int out_size, void* d_ws, size_t ws_size,
                              hipStream_t stream) {
    const int*   x    = (const int*)d_in[0];    // (B, L) int32
    const float* emb  = (const float*)d_in[1];  // (V, D) fp32
    const float* W    = (const float*)d_in[2];  // (V, D*(N-1)) fp32
    const float* bias = (const float*)d_in[3];  // (V,) fp32
    float*       out  = (float*)d_out;          // (B, L, V) fp32

    // 4 v-quarters x 64 position-half-blocks = 256 blocks = 1/CU.
    // Single dispatch: no build_table kernel, no T round-trip, no launch gap.
    fused_ngram_kernel<<<256, 512, 0, stream>>>(x, emb, W, bias, out);
}

// Round 6
// 92.139 us; speedup vs baseline: 3.4513x; 3.4513x over previous
//
#include <hip/hip_runtime.h>

// Problem constants (from reference): B=32, L=4096, D=128, N=5, V=128
constexpr int Bn = 32;
constexpr int Ln = 4096;
constexpr int Dn = 128;
constexpr int Vn = 128;
constexpr int N1 = 4;  // N - 1 context slots

typedef float vfloat4 __attribute__((ext_vector_type(4)));  // native vec for nontemporal builtins

// R12: revert to the proven two-kernel structure (R0 ~92.3us) + deeper MLP in ngram.
// R5 post-mortem (counters): fused per-block table build re-reads the W-quarter
// 128x -> 2.2 GB of L2 traffic, 256us kernel, VALUBusy 7.7%. Fusion is dead.
// R0-R3 established: gather path (L2 vs LDS vs swizzled LDS) neutral; store shape
// (512B contig vs 128B chunks) neutral; ngram sits ~3x off the write roofline on
// latency exposure. R12 attacks that: 8 positions/thread, x-window preloaded
// (3 int4s), two fully-unrolled 16-gather batches -> fewer serial chains per
// byte stored, 16 independent loads in flight per batch.
//
// Kernel A: T[k][t][v] = dot(emb[t], W[v, k*D:(k+1)*D]) (+ bias[v] for k==0).
// grid 512 blocks x 128 thr. (R4/R6 prior session: coalesced/transposed variants
// neutral-to-worse; keep this latency-hidden form.)
__global__ void build_table_kernel(const float* __restrict__ emb,
                                   const float* __restrict__ W,
                                   const float* __restrict__ bias,
                                   float* __restrict__ T) {
    const int kt = blockIdx.x;        // k*128 + t
    const int k  = kt >> 7;
    const int t  = kt & 127;
    const int v  = threadIdx.x;       // 0..127

    __shared__ float4 e[Dn / 4];
    if (threadIdx.x < Dn / 4) {
        e[threadIdx.x] = ((const float4*)(emb + t * Dn))[threadIdx.x];
    }
    __syncthreads();

    const float4* w = (const float4*)(W + (size_t)v * (Dn * N1) + k * Dn);
    float acc = (k == 0) ? bias[v] : 0.f;  // fold bias into slot-0 table
#pragma unroll
    for (int i = 0; i < Dn / 4; ++i) {
        float4 wv = w[i];
        float4 ev = e[i];
        acc += wv.x * ev.x + wv.y * ev.y + wv.z * ev.z + wv.w * ev.w;
    }
    T[(size_t)kt * Vn + v] = acc;  // plain [4][128][128] layout
}

// Kernel B: out[b,j,v] = sum_k T[k][x[b,j-4+k]][v], bias folded into T[0].
// Thread handles 8 consecutive positions x one float4 of v. Wave = 2 groups x
// 32 vq lanes -> every gather instruction reads a CONTIGUOUS 512 B table row
// (broadcast-friendly, 8 lines max), every NT-store instruction writes 2 x 512 B
// contiguous. All x ints preloaded; two 16-gather unrolled batches per thread.
__global__ void __launch_bounds__(256, 4)
ngram_logits_kernel(const int* __restrict__ x,
                    const float* __restrict__ T,
                    const float* __restrict__ bias,
                    float* __restrict__ out) {
    const int tid = blockIdx.x * 256 + threadIdx.x;
    const int vq  = tid & 31;          // float4 column within the full 128-v row
    const int G   = tid >> 5;          // 8-position group, 0..16383
    const int basepos = G << 3;        // 8-aligned
    const int j0      = basepos & (Ln - 1);

    const vfloat4* Tq   = (const vfloat4*)T;  // [512 rows][32 float4]
    vfloat4*       outq = (vfloat4*)out;
    vfloat4*       ob   = outq + (size_t)basepos * 32 + vq;

    // token window w[0..10] = x[basepos-4 .. basepos+6] (indices const post-unroll)
    int w[11];
    const int4 xb = *(const int4*)(x + basepos);
    const int4 xc = *(const int4*)(x + basepos + 4);
    w[4] = xb.x; w[5] = xb.y; w[6] = xb.z; w[7] = xb.w;
    w[8] = xc.x; w[9] = xc.y; w[10] = xc.z;

    if (j0 == 0) {
        // positions 0..3 of a batch row: bias-only (w[0..3] unused)
        const vfloat4 bv = ((const vfloat4*)bias)[vq];
#pragma unroll
        for (int i = 0; i < 4; ++i)
            __builtin_nontemporal_store(bv, ob + i * 32);
    } else {
        const int4 xa = *(const int4*)(x + basepos - 4);
        w[0] = xa.x; w[1] = xa.y; w[2] = xa.z; w[3] = xa.w;
        // batch 0: positions 0..3 — 16 independent gathers, then 4 NT stores
        vfloat4 a0 = Tq[(size_t)(0 * Vn + w[0]) * 32 + vq];
        vfloat4 a1 = Tq[(size_t)(0 * Vn + w[1]) * 32 + vq];
        vfloat4 a2 = Tq[(size_t)(0 * Vn + w[2]) * 32 + vq];
        vfloat4 a3 = Tq[(size_t)(0 * Vn + w[3]) * 32 + vq];
#pragma unroll
        for (int k = 1; k < N1; ++k) {
            a0 += Tq[(size_t)(k * Vn + w[0 + k]) * 32 + vq];
            a1 += Tq[(size_t)(k * Vn + w[1 + k]) * 32 + vq];
            a2 += Tq[(size_t)(k * Vn + w[2 + k]) * 32 + vq];
            a3 += Tq[(size_t)(k * Vn + w[3 + k]) * 32 + vq];
        }
        __builtin_nontemporal_store(a0, ob + 0 * 32);
        __builtin_nontemporal_store(a1, ob + 1 * 32);
        __builtin_nontemporal_store(a2, ob + 2 * 32);
        __builtin_nontemporal_store(a3, ob + 3 * 32);
    }

    // batch 1: positions 4..7 (always valid; window entirely within this row)
    {
        vfloat4 a0 = Tq[(size_t)(0 * Vn + w[4]) * 32 + vq];
        vfloat4 a1 = Tq[(size_t)(0 * Vn + w[5]) * 32 + vq];
        vfloat4 a2 = Tq[(size_t)(0 * Vn + w[6]) * 32 + vq];
        vfloat4 a3 = Tq[(size_t)(0 * Vn + w[7]) * 32 + vq];
#pragma unroll
        for (int k = 1; k < N1; ++k) {
            a0 += Tq[(size_t)(k * Vn + w[4 + k]) * 32 + vq];
            a1 += Tq[(size_t)(k * Vn + w[5 + k]) * 32 + vq];
            a2 += Tq[(size_t)(k * Vn + w[6 + k]) * 32 + vq];
            a3 += Tq[(size_t)(k * Vn + w[7 + k]) * 32 + vq];
        }
        __builtin_nontemporal_store(a0, ob + 4 * 32);
        __builtin_nontemporal_store(a1, ob + 5 * 32);
        __builtin_nontemporal_store(a2, ob + 6 * 32);
        __builtin_nontemporal_store(a3, ob + 7 * 32);
    }
}

extern "C" void kernel_launch(void* const* d_in, const int* in_sizes, int n_in,
                              void* d_out, int out_size, void* d_ws, size_t ws_size,
                              hipStream_t stream) {
    const int*   x    = (const int*)d_in[0];    // (B, L) int32
    const float* emb  = (const float*)d_in[1];  // (V, D) fp32
    const float* W    = (const float*)d_in[2];  // (V, D*(N-1)) fp32
    const float* bias = (const float*)d_in[3];  // (V,) fp32
    float*       out  = (float*)d_out;          // (B, L, V) fp32
    float*       T    = (float*)d_ws;           // (4, 128, 128) fp32 = 256 KiB

    build_table_kernel<<<N1 * Vn, Vn, 0, stream>>>(emb, W, bias, T);

    // 16384 position-groups x 32 v-columns / 256 threads = 2048 blocks
    ngram_logits_kernel<<<2048, 256, 0, stream>>>(x, T, bias, out);
}